// Round 1
// baseline (203.534 us; speedup 1.0000x reference)
//
#include <hip/hip_runtime.h>

#define NEG_INF (-1e30f)
#define GUARD   (-5e29f)

constexpr int T = 512, N = 32, C = 4000, S = 64;
constexpr int TN = T * N;
constexpr int LPW = S + 1;  // 65: [blank, label_0..label_63] log-probs per (t,n)

// Kernel 1: per (t,n) row of C=4000 logits, compute streaming logsumexp and
// emit log-softmax at the 65 needed classes. One wave per row, 4 waves/block.
__global__ __launch_bounds__(256) void k_logsoftmax_gather(
    const float* __restrict__ x, const int* __restrict__ labels,
    float* __restrict__ lp)
{
    int row  = blockIdx.x * 4 + (threadIdx.x >> 6);   // row = t*N + n
    int lane = threadIdx.x & 63;
    const float*  rp  = x + (size_t)row * C;
    const float4* rp4 = reinterpret_cast<const float4*>(rp);

    float m = -INFINITY, s = 0.f;
    for (int i = lane; i < C / 4; i += 64) {          // C/4 = 1000 float4s
        float4 v = rp4[i];
        float mv = fmaxf(fmaxf(v.x, v.y), fmaxf(v.z, v.w));
        float s4 = __expf(v.x - mv) + __expf(v.y - mv) +
                   __expf(v.z - mv) + __expf(v.w - mv);
        float nm = fmaxf(m, mv);
        s = s * __expf(m - nm) + s4 * __expf(mv - nm);
        m = nm;
    }
    // wave-wide (m, s) combine
    for (int off = 32; off > 0; off >>= 1) {
        float om = __shfl_xor(m, off);
        float os = __shfl_xor(s, off);
        float nm = fmaxf(m, om);
        s = s * __expf(m - nm) + os * __expf(om - nm);
        m = nm;
    }
    float logZ = m + __logf(s);

    int n = row % N;
    int c = labels[n * S + lane];                     // lane i -> label s=i
    float* outp = lp + (size_t)row * LPW;
    outp[1 + lane] = rp[c] - logZ;
    if (lane == 0) outp[0] = rp[0] - logZ;            // blank
}

// Kernel 2: alpha recursion. One wave per batch element n.
// Lane i owns extended positions l=2i (blank) and l=2i+1 (label s=i);
// lane 63 additionally owns l=128 (final blank).
// Even (blank) positions never use the l-2 transition, so the only cross-lane
// dependency per step is prev lane's odd alpha: one shfl_up per t.
__global__ __launch_bounds__(64) void k_ctc_alpha(
    const float* __restrict__ lp, const int* __restrict__ labels,
    const int* __restrict__ input_len, const int* __restrict__ label_len,
    float* __restrict__ loss_out)
{
    int n    = blockIdx.x;
    int lane = threadIdx.x;
    int Tin  = input_len[n];
    int Sl   = label_len[n];

    int li   = labels[n * S + lane];
    int lim1 = (lane > 0) ? labels[n * S + lane - 1] : -1;
    bool skip_ok = (lane > 0) && (li != 0) && (li != lim1);

    const float* base = lp + (size_t)n * LPW;         // + t*N*LPW walks time

    // t = 0 init
    float a0 = (lane == 0) ? base[0] : NEG_INF;                       // alpha[0]
    float a1 = (lane == 0) ? ((Sl > 0) ? base[1] : NEG_INF) : NEG_INF; // alpha[1]
    float aX = NEG_INF;                                                // alpha[128]

    // prefetch t = 1
    float nb = base[(size_t)N * LPW];
    float nl = base[(size_t)N * LPW + 1 + lane];

    for (int t = 1; t < T; ++t) {
        float cb = nb, cl = nl;
        if (t + 1 < T) {
            size_t o = (size_t)(t + 1) * N * LPW;
            nb = base[o];
            nl = base[o + 1 + lane];
        }
        float p_a1 = __shfl_up(a1, 1);                // alpha[2i-1]
        if (lane == 0) p_a1 = NEG_INF;

        // even pos l=2i: from alpha[l], alpha[l-1] (skip never allowed at blank)
        float m2 = fmaxf(a0, p_a1);
        float s2 = __expf(a0 - m2) + __expf(p_a1 - m2);
        float na0 = (m2 > GUARD) ? (m2 + __logf(s2) + cb) : NEG_INF;

        // odd pos l=2i+1: from alpha[l], alpha[l-1]=a0, alpha[l-2]=p_a1 (if skip)
        float a2v = skip_ok ? p_a1 : NEG_INF;
        float m3 = fmaxf(fmaxf(a1, a0), a2v);
        float s3 = __expf(a1 - m3) + __expf(a0 - m3) + __expf(a2v - m3);
        float na1 = (m3 > GUARD) ? (m3 + __logf(s3) + cl) : NEG_INF;

        // pos 128 (only lane 63's value is kept): from alpha[128], alpha[127]=a1
        float mX = fmaxf(aX, a1);
        float sX = __expf(aX - mX) + __expf(a1 - mX);
        float naX = (mX > GUARD) ? (mX + __logf(sX) + cb) : NEG_INF;

        bool act = (t < Tin);
        a0 = act ? na0 : a0;
        a1 = act ? na1 : a1;
        aX = act ? naX : aX;
    }

    // loss_n = -logsumexp(alpha[2*Sl], alpha[2*Sl-1])
    int idx = 2 * Sl;
    float a_last = (idx >= 2 * S) ? __shfl(aX, 63) : __shfl(a0, Sl);
    float a_prev_raw = __shfl(a1, (Sl > 0) ? (Sl - 1) : 0);
    float a_prev = (Sl > 0) ? a_prev_raw : NEG_INF;
    if (lane == 0) {
        float m  = fmaxf(a_last, a_prev);
        float ll = m + __logf(__expf(a_last - m) + __expf(a_prev - m));
        float loss = -ll;
        if (!(loss < 5e29f)) loss = 0.f;              // zero_infinity (NaN -> 0 too)
        loss_out[n] = loss;
    }
}

// Kernel 3: sum the N per-batch losses into d_out[0].
__global__ __launch_bounds__(64) void k_reduce(
    const float* __restrict__ loss, float* __restrict__ out)
{
    int lane = threadIdx.x;
    float v = (lane < N) ? loss[lane] : 0.f;
    for (int off = 32; off > 0; off >>= 1) v += __shfl_xor(v, off);
    if (lane == 0) out[0] = v;
}

extern "C" void kernel_launch(void* const* d_in, const int* in_sizes, int n_in,
                              void* d_out, int out_size, void* d_ws, size_t ws_size,
                              hipStream_t stream) {
    const float* x       = (const float*)d_in[0];
    const int*   labels  = (const int*)d_in[1];
    const int*   in_len  = (const int*)d_in[2];
    const int*   lab_len = (const int*)d_in[3];
    float* out  = (float*)d_out;
    float* lp   = (float*)d_ws;                        // TN*65 floats = 4.26 MB
    float* loss = lp + (size_t)TN * LPW;               // + N floats

    k_logsoftmax_gather<<<TN / 4, 256, 0, stream>>>(x, labels, lp);
    k_ctc_alpha<<<N, 64, 0, stream>>>(lp, labels, in_len, lab_len, loss);
    k_reduce<<<1, 64, 0, stream>>>(loss, out);
}